// Round 1
// baseline (26.330 us; speedup 1.0000x reference)
//
#include <hip/hip_runtime.h>
#include <hip/hip_bf16.h>

// out[b, 0, h, w] = min over c of x[b, T-1, c, h, w]
// x: [B=4, T=8, C=32, H=512, W=512] float32, contiguous.
// Pure memory-bound channel-reduction over the last timestep.

__global__ void __launch_bounds__(256)
min_last_t_kernel(const float4* __restrict__ x, float4* __restrict__ out) {
    constexpr int HW4   = (512 * 512) / 4;   // float4s per image plane
    constexpr int C     = 32;
    constexpr int CHW4  = C * HW4;           // float4s per [C,H,W] block
    constexpr int TCHW4 = 8 * CHW4;          // float4s per [T,C,H,W] block

    int i = blockIdx.x * blockDim.x + threadIdx.x;  // [0, B*HW4)
    int b = i / HW4;
    int p = i - b * HW4;

    const float4* base = x + (size_t)b * TCHW4 + (size_t)7 * CHW4 + p;

    float4 m = base[0];
    #pragma unroll
    for (int c = 1; c < C; ++c) {
        float4 v = base[(size_t)c * HW4];
        m.x = fminf(m.x, v.x);
        m.y = fminf(m.y, v.y);
        m.z = fminf(m.z, v.z);
        m.w = fminf(m.w, v.w);
    }
    out[i] = m;
}

extern "C" void kernel_launch(void* const* d_in, const int* in_sizes, int n_in,
                              void* d_out, int out_size, void* d_ws, size_t ws_size,
                              hipStream_t stream) {
    const float4* x = (const float4*)d_in[0];
    float4* out = (float4*)d_out;

    // B*HW/4 float4 outputs = 4 * 512*512 / 4 = 262144 threads
    constexpr int n4 = 4 * (512 * 512) / 4;
    constexpr int block = 256;
    constexpr int grid = n4 / block;  // 1024

    min_last_t_kernel<<<grid, block, 0, stream>>>(x, out);
}

// Round 2
// 25.170 us; speedup vs baseline: 1.0461x; 1.0461x over previous
//
#include <hip/hip_runtime.h>
#include <hip/hip_bf16.h>

// out[b, 0, h, w] = min over c of x[b, T-1, c, h, w]
// x: [B=4, T=8, C=32, H=512, W=512] float32, contiguous.
// Pure memory-bound channel-reduction over the last timestep.
// Read 134 MB + write 4.2 MB; HBM-bound (L3 flushed between replays by
// the harness's 4.3 GB input-restore fill).

typedef float f32x4 __attribute__((ext_vector_type(4)));

__global__ void __launch_bounds__(256)
min_last_t_kernel(const f32x4* __restrict__ x, f32x4* __restrict__ out) {
    constexpr int HW4   = (512 * 512) / 4;   // 65536 float4s per plane
    constexpr int C     = 32;
    constexpr int CHW4  = C * HW4;
    constexpr int TCHW4 = 8 * CHW4;

    int i = blockIdx.x * blockDim.x + threadIdx.x;  // [0, B*HW4)
    int b = i >> 16;            // / HW4
    int p = i & (HW4 - 1);      // % HW4

    const f32x4* base = x + (size_t)b * TCHW4 + (size_t)7 * CHW4 + p;

    // Stagger channel start per block: spreads instantaneous HBM traffic
    // over the whole 128 MiB footprint instead of all waves hitting c=0 first.
    int c0 = blockIdx.x & (C - 1);

    f32x4 m = __builtin_nontemporal_load(base + (size_t)c0 * HW4);
    #pragma unroll
    for (int k = 1; k < C; ++k) {
        int c = (c0 + k) & (C - 1);
        f32x4 v = __builtin_nontemporal_load(base + (size_t)c * HW4);
        m[0] = fminf(m[0], v[0]);
        m[1] = fminf(m[1], v[1]);
        m[2] = fminf(m[2], v[2]);
        m[3] = fminf(m[3], v[3]);
    }
    __builtin_nontemporal_store(m, out + i);
}

extern "C" void kernel_launch(void* const* d_in, const int* in_sizes, int n_in,
                              void* d_out, int out_size, void* d_ws, size_t ws_size,
                              hipStream_t stream) {
    const f32x4* x = (const f32x4*)d_in[0];
    f32x4* out = (f32x4*)d_out;

    constexpr int n4 = 4 * (512 * 512) / 4;  // 262144 output float4s
    constexpr int block = 256;
    constexpr int grid = n4 / block;         // 1024 blocks = 16 waves/CU

    min_last_t_kernel<<<grid, block, 0, stream>>>(x, out);
}